// Round 3
// baseline (79.330 us; speedup 1.0000x reference)
//
#include <hip/hip_runtime.h>
#include <stdint.h>

#define S_INV (1.0f / 7.0f)
#define COORD_W 5.0f
#define NOOBJ_W 0.5f

// Per-wave micro-chunk: 64 cells (lane == cell), both tensors staged linearly
// into the wave's PRIVATE 15360-B LDS slice via global_load_lds (width 16).
// No __syncthreads in the hot loop -- only wave-local s_waitcnt vmcnt(0).
// Slice layout (bytes): [0,7680) = 64 'out' cells, [7680,15360) = 64 'tgt'.
#define SLICE_FLOATS 3840   // 15360 B
#define WAVES_PER_BLOCK 4

typedef const __attribute__((address_space(1))) void* gp1_t;
typedef __attribute__((address_space(3))) void* lp3_t;

__global__ __launch_bounds__(256) void yolo_loss_kernel(
    const float* __restrict__ outp, const float* __restrict__ tgtp,
    float* __restrict__ ws, int nchunks, int nwaves)
{
    __shared__ float lds[WAVES_PER_BLOCK * SLICE_FLOATS];

    const int wave = threadIdx.x >> 6;
    const int lane = threadIdx.x & 63;
    const int gwave = blockIdx.x * WAVES_PER_BLOCK + wave;

    float* slice = lds + wave * SLICE_FLOATS;

    float acc_total = 0.f, acc_iou = 0.f, acc_acc = 0.f;

    for (int m = gwave; m < nchunks; m += nwaves) {
        const size_t cbase = (size_t)m * (64 * 120);   // chunk byte offset

        // ---- stage 15360 B: 15 x global_load_lds_dwordx4 (async DMA) ----
#pragma unroll
        for (int j = 0; j < 15; ++j) {
            const int off = j * 1024 + lane * 16;      // linear byte in slice
            const char* src = (off < 7680)
                ? (const char*)outp + cbase + off
                : (const char*)tgtp + cbase + (off - 7680);
            __builtin_amdgcn_global_load_lds((gp1_t)src,
                                             (lp3_t)(slice + j * 256),
                                             16, 0, 0);
        }
        asm volatile("s_waitcnt vmcnt(0)" ::: "memory");
        __builtin_amdgcn_sched_barrier(0);   // rule #18: fence reads below wait

        // ---- read own cell (linear layout; 4-way bank alias, acceptable) ----
        const float* oc = slice + lane * 30;
        const float* tc = slice + 1920 + lane * 30;
        float ov[30], tv[30];
#pragma unroll
        for (int i = 0; i < 15; ++i) {
            float2 a = *reinterpret_cast<const float2*>(oc + 2 * i);
            float2 b = *reinterpret_cast<const float2*>(tc + 2 * i);
            ov[2 * i] = a.x; ov[2 * i + 1] = a.y;
            tv[2 * i] = b.x; tv[2 * i + 1] = b.y;
        }

        float w_obj = (tv[4] > 0.f) ? 1.f : 0.f;
        float w_no = 1.f - w_obj;

        // class loss + argmax accuracy (first-max tie-break)
        float cls = 0.f;
        float omax = ov[10]; int oarg = 0;
        float tmax = tv[10]; int targ = 0;
#pragma unroll
        for (int c = 0; c < 20; ++c) {
            float d = ov[10 + c] - tv[10 + c];
            cls += d * d;
            if (ov[10 + c] > omax) { omax = ov[10 + c]; oarg = c; }
            if (tv[10 + c] > tmax) { tmax = tv[10 + c]; targ = c; }
        }

        // IOU of both predicted boxes vs target box 0
        float t_x = tv[0] * S_INV, t_y = tv[1] * S_INV;
        float t_w = tv[2], t_h = tv[3];
        float t_l = t_x - 0.5f * t_w, t_r = t_x + 0.5f * t_w;
        float t_t = t_y - 0.5f * t_h, t_b = t_y + 0.5f * t_h;
        float area_t = t_w * t_h;

        float iou0, iou1;
        {
            float x = ov[0] * S_INV, y = ov[1] * S_INV;
            float w = ov[2], h = ov[3];
            float l = x - 0.5f * w, r = x + 0.5f * w;
            float tt = y - 0.5f * h, bb = y + 0.5f * h;
            float iw = fmaxf(fminf(r, t_r) - fmaxf(l, t_l), 0.f);
            float ih = fmaxf(fminf(bb, t_b) - fmaxf(tt, t_t), 0.f);
            float inter = iw * ih;
            iou0 = inter / (w * h + area_t - inter);
        }
        {
            float x = ov[5] * S_INV, y = ov[6] * S_INV;
            float w = ov[7], h = ov[8];
            float l = x - 0.5f * w, r = x + 0.5f * w;
            float tt = y - 0.5f * h, bb = y + 0.5f * h;
            float iw = fmaxf(fminf(r, t_r) - fmaxf(l, t_l), 0.f);
            float ih = fmaxf(fminf(bb, t_b) - fmaxf(tt, t_t), 0.f);
            float inter = iw * ih;
            iou1 = inter / (w * h + area_t - inter);
        }

        bool r1 = (iou1 > iou0);
        float max_iou = r1 ? iou1 : iou0;

        float os0 = r1 ? ov[5] : ov[0];
        float os1 = r1 ? ov[6] : ov[1];
        float os2 = r1 ? ov[7] : ov[2];
        float os3 = r1 ? ov[8] : ov[3];
        float os4 = r1 ? ov[9] : ov[4];
        float ts0 = r1 ? tv[5] : tv[0];
        float ts1 = r1 ? tv[6] : tv[1];
        float ts2 = r1 ? tv[7] : tv[2];
        float ts3 = r1 ? tv[8] : tv[3];
        float oa4 = r1 ? ov[4] : ov[9];

        float d0 = os0 - ts0, d1 = os1 - ts1;
        float d2 = sqrtf(os2) - sqrtf(ts2);
        float d3 = sqrtf(os3) - sqrtf(ts3);
        float coord = d0 * d0 + d1 * d1 + d2 * d2 + d3 * d3;

        float dc = os4 - max_iou;
        float conf = dc * dc;
        float aband = oa4 * oa4;
        float n0 = ov[4] - tv[4], n1 = ov[9] - tv[9];
        float noobj = n0 * n0 + n1 * n1;

        float cell_total = w_obj * (COORD_W * coord + conf + NOOBJ_W * aband + cls)
                         + NOOBJ_W * w_no * noobj;

        acc_total += cell_total;
        acc_iou   += w_obj * max_iou;
        acc_acc   += w_obj * ((oarg == targ) ? 1.f : 0.f);

        __builtin_amdgcn_sched_barrier(0);   // next stage must not hoist above reads (WAR)
    }

    // ---- wave-local reduction; lane 0 writes SoA partials (no barriers) ----
#pragma unroll
    for (int off = 32; off > 0; off >>= 1) {
        acc_total += __shfl_down(acc_total, off);
        acc_iou   += __shfl_down(acc_iou, off);
        acc_acc   += __shfl_down(acc_acc, off);
    }
    if (lane == 0) {
        ws[gwave]              = acc_total;
        ws[nwaves + gwave]     = acc_iou;
        ws[2 * nwaves + gwave] = acc_acc;
    }
}

__global__ __launch_bounds__(256) void yolo_reduce_kernel(
    const float* __restrict__ ws, float* __restrict__ out, int nwaves)
{
    float t0 = 0.f, t1 = 0.f, t2 = 0.f;
    for (int i = threadIdx.x; i < nwaves; i += blockDim.x) {
        t0 += ws[i];
        t1 += ws[nwaves + i];
        t2 += ws[2 * nwaves + i];
    }
#pragma unroll
    for (int off = 32; off > 0; off >>= 1) {
        t0 += __shfl_down(t0, off);
        t1 += __shfl_down(t1, off);
        t2 += __shfl_down(t2, off);
    }
    __shared__ float s[3][4];
    int wave = threadIdx.x >> 6;
    int lane = threadIdx.x & 63;
    if (lane == 0) { s[0][wave] = t0; s[1][wave] = t1; s[2][wave] = t2; }
    __syncthreads();
    if (threadIdx.x == 0) {
        float a0 = 0.f, a1 = 0.f, a2 = 0.f;
#pragma unroll
        for (int w = 0; w < 4; ++w) { a0 += s[0][w]; a1 += s[1][w]; a2 += s[2][w]; }
        out[0] = a0;   // total
        out[1] = a1;   // sum_iou
        out[2] = a2;   // accurate_num
    }
}

extern "C" void kernel_launch(void* const* d_in, const int* in_sizes, int n_in,
                              void* d_out, int out_size, void* d_ws, size_t ws_size,
                              hipStream_t stream) {
    const float* outp = (const float*)d_in[0];
    const float* tgtp = (const float*)d_in[1];
    float* ws = (float*)d_ws;
    float* o = (float*)d_out;

    const int ncells  = in_sizes[0] / 30;     // 32768*7*7 = 1,605,632
    const int nchunks = ncells / 64;          // 25,088 (exact)
    const int blocks  = 2048;
    const int nwaves  = blocks * WAVES_PER_BLOCK;   // 8192

    yolo_loss_kernel<<<blocks, 256, 0, stream>>>(outp, tgtp, ws, nchunks, nwaves);
    yolo_reduce_kernel<<<1, 256, 0, stream>>>(ws, o, nwaves);
}

// Round 4
// 73.939 us; speedup vs baseline: 1.0729x; 1.0729x over previous
//
#include <hip/hip_runtime.h>
#include <stdint.h>

#define S_INV (1.0f / 7.0f)
#define COORD_W 5.0f
#define NOOBJ_W 0.5f

// Per-wave double-buffered micro-chunks: 64 cells (lane == cell), both tensors
// staged linearly into the wave's PRIVATE LDS slice pair via global_load_lds
// (width 16). Counted vmcnt(15) in steady state -- the wave NEVER drains its
// pipe (T3/T4). No __syncthreads anywhere in the hot loop. Persistent grid:
// 256 blocks = 1 per CU, 4 waves/CU, ~24 chunks per wave.
// Slice layout (bytes): [0,7680) = 64 'out' cells, [7680,15360) = 64 'tgt'.
#define SLICE_FLOATS 3840          // 15360 B per buffer
#define WAVES_PER_BLOCK 4

typedef const __attribute__((address_space(1))) void* gp1_t;
typedef __attribute__((address_space(3))) void* lp3_t;

__device__ __forceinline__ void stage_chunk(const float* __restrict__ outp,
                                            const float* __restrict__ tgtp,
                                            float* dst, int m, int lane)
{
    const size_t cb = (size_t)m * (64 * 120);   // chunk byte offset
#pragma unroll
    for (int j = 0; j < 15; ++j) {
        const int off = j * 1024 + lane * 16;   // linear byte within slice
        const char* src = (off < 7680)
            ? (const char*)outp + cb + off
            : (const char*)tgtp + cb + (off - 7680);
        // LDS dest is wave-uniform base + lane*16 (HW adds lane offset).
        __builtin_amdgcn_global_load_lds((gp1_t)src, (lp3_t)(dst + j * 256),
                                         16, 0, 0);
    }
}

__global__ __launch_bounds__(256) void yolo_loss_kernel(
    const float* __restrict__ outp, const float* __restrict__ tgtp,
    float* __restrict__ ws, int nchunks, int nwaves)
{
    __shared__ float lds[WAVES_PER_BLOCK * 2 * SLICE_FLOATS];   // 122880 B

    const int wave = threadIdx.x >> 6;
    const int lane = threadIdx.x & 63;
    const int gwave = blockIdx.x * WAVES_PER_BLOCK + wave;

    float* bufA = lds + wave * 2 * SLICE_FLOATS;
    float* bufB = bufA + SLICE_FLOATS;

    float acc_total = 0.f, acc_iou = 0.f, acc_acc = 0.f;

    if (gwave < nchunks) stage_chunk(outp, tgtp, bufA, gwave, lane);
    int cur = 0;

    for (int m = gwave; m < nchunks; m += nwaves) {
        const bool has_next = (m + nwaves) < nchunks;   // wave-uniform
        float* bnext = cur ? bufA : bufB;
        float* bcur  = cur ? bufB : bufA;

        if (has_next) {
            stage_chunk(outp, tgtp, bnext, m + nwaves, lane);
            // outstanding = 30; wait until 15 -> current buffer complete,
            // next buffer's 15 loads stay in flight across the compute.
            asm volatile("s_waitcnt vmcnt(15)" ::: "memory");
        } else {
            asm volatile("s_waitcnt vmcnt(0)" ::: "memory");
        }
        __builtin_amdgcn_sched_barrier(0);   // rule #18: no reads above the wait

        // ---- read own cell (linear layout; 4-way bank alias, ~free here) ----
        const float* oc = bcur + lane * 30;
        const float* tc = bcur + 1920 + lane * 30;
        float ov[30], tv[30];
#pragma unroll
        for (int i = 0; i < 15; ++i) {
            float2 a = *reinterpret_cast<const float2*>(oc + 2 * i);
            float2 b = *reinterpret_cast<const float2*>(tc + 2 * i);
            ov[2 * i] = a.x; ov[2 * i + 1] = a.y;
            tv[2 * i] = b.x; tv[2 * i + 1] = b.y;
        }

        float w_obj = (tv[4] > 0.f) ? 1.f : 0.f;
        float w_no = 1.f - w_obj;

        // class loss + argmax accuracy (first-max tie-break)
        float cls = 0.f;
        float omax = ov[10]; int oarg = 0;
        float tmax = tv[10]; int targ = 0;
#pragma unroll
        for (int c = 0; c < 20; ++c) {
            float d = ov[10 + c] - tv[10 + c];
            cls += d * d;
            if (ov[10 + c] > omax) { omax = ov[10 + c]; oarg = c; }
            if (tv[10 + c] > tmax) { tmax = tv[10 + c]; targ = c; }
        }

        // IOU of both predicted boxes vs target box 0
        float t_x = tv[0] * S_INV, t_y = tv[1] * S_INV;
        float t_w = tv[2], t_h = tv[3];
        float t_l = t_x - 0.5f * t_w, t_r = t_x + 0.5f * t_w;
        float t_t = t_y - 0.5f * t_h, t_b = t_y + 0.5f * t_h;
        float area_t = t_w * t_h;

        float iou0, iou1;
        {
            float x = ov[0] * S_INV, y = ov[1] * S_INV;
            float w = ov[2], h = ov[3];
            float l = x - 0.5f * w, r = x + 0.5f * w;
            float tt = y - 0.5f * h, bb = y + 0.5f * h;
            float iw = fmaxf(fminf(r, t_r) - fmaxf(l, t_l), 0.f);
            float ih = fmaxf(fminf(bb, t_b) - fmaxf(tt, t_t), 0.f);
            float inter = iw * ih;
            iou0 = inter / (w * h + area_t - inter);
        }
        {
            float x = ov[5] * S_INV, y = ov[6] * S_INV;
            float w = ov[7], h = ov[8];
            float l = x - 0.5f * w, r = x + 0.5f * w;
            float tt = y - 0.5f * h, bb = y + 0.5f * h;
            float iw = fmaxf(fminf(r, t_r) - fmaxf(l, t_l), 0.f);
            float ih = fmaxf(fminf(bb, t_b) - fmaxf(tt, t_t), 0.f);
            float inter = iw * ih;
            iou1 = inter / (w * h + area_t - inter);
        }

        bool r1 = (iou1 > iou0);
        float max_iou = r1 ? iou1 : iou0;

        float os0 = r1 ? ov[5] : ov[0];
        float os1 = r1 ? ov[6] : ov[1];
        float os2 = r1 ? ov[7] : ov[2];
        float os3 = r1 ? ov[8] : ov[3];
        float os4 = r1 ? ov[9] : ov[4];
        float ts0 = r1 ? tv[5] : tv[0];
        float ts1 = r1 ? tv[6] : tv[1];
        float ts2 = r1 ? tv[7] : tv[2];
        float ts3 = r1 ? tv[8] : tv[3];
        float oa4 = r1 ? ov[4] : ov[9];

        float d0 = os0 - ts0, d1 = os1 - ts1;
        float d2 = sqrtf(os2) - sqrtf(ts2);
        float d3 = sqrtf(os3) - sqrtf(ts3);
        float coord = d0 * d0 + d1 * d1 + d2 * d2 + d3 * d3;

        float dc = os4 - max_iou;
        float conf = dc * dc;
        float aband = oa4 * oa4;
        float n0 = ov[4] - tv[4], n1 = ov[9] - tv[9];
        float noobj = n0 * n0 + n1 * n1;

        float cell_total = w_obj * (COORD_W * coord + conf + NOOBJ_W * aband + cls)
                         + NOOBJ_W * w_no * noobj;

        acc_total += cell_total;
        acc_iou   += w_obj * max_iou;
        acc_acc   += w_obj * ((oarg == targ) ? 1.f : 0.f);

        __builtin_amdgcn_sched_barrier(0);   // WAR: next STAGE stays below reads
        cur ^= 1;
    }

    // ---- wave-local reduction; lane 0 writes SoA partials (no barriers) ----
#pragma unroll
    for (int off = 32; off > 0; off >>= 1) {
        acc_total += __shfl_down(acc_total, off);
        acc_iou   += __shfl_down(acc_iou, off);
        acc_acc   += __shfl_down(acc_acc, off);
    }
    if (lane == 0) {
        ws[gwave]              = acc_total;
        ws[nwaves + gwave]     = acc_iou;
        ws[2 * nwaves + gwave] = acc_acc;
    }
}

__global__ __launch_bounds__(256) void yolo_reduce_kernel(
    const float* __restrict__ ws, float* __restrict__ out, int nwaves)
{
    float t0 = 0.f, t1 = 0.f, t2 = 0.f;
    for (int i = threadIdx.x; i < nwaves; i += blockDim.x) {
        t0 += ws[i];
        t1 += ws[nwaves + i];
        t2 += ws[2 * nwaves + i];
    }
#pragma unroll
    for (int off = 32; off > 0; off >>= 1) {
        t0 += __shfl_down(t0, off);
        t1 += __shfl_down(t1, off);
        t2 += __shfl_down(t2, off);
    }
    __shared__ float s[3][4];
    int wave = threadIdx.x >> 6;
    int lane = threadIdx.x & 63;
    if (lane == 0) { s[0][wave] = t0; s[1][wave] = t1; s[2][wave] = t2; }
    __syncthreads();
    if (threadIdx.x == 0) {
        float a0 = 0.f, a1 = 0.f, a2 = 0.f;
#pragma unroll
        for (int w = 0; w < 4; ++w) { a0 += s[0][w]; a1 += s[1][w]; a2 += s[2][w]; }
        out[0] = a0;   // total
        out[1] = a1;   // sum_iou
        out[2] = a2;   // accurate_num
    }
}

extern "C" void kernel_launch(void* const* d_in, const int* in_sizes, int n_in,
                              void* d_out, int out_size, void* d_ws, size_t ws_size,
                              hipStream_t stream) {
    const float* outp = (const float*)d_in[0];
    const float* tgtp = (const float*)d_in[1];
    float* ws = (float*)d_ws;
    float* o = (float*)d_out;

    const int ncells  = in_sizes[0] / 30;           // 32768*7*7 = 1,605,632
    const int nchunks = ncells / 64;                // 25,088 (exact)
    const int blocks  = 256;                        // persistent: 1 block/CU
    const int nwaves  = blocks * WAVES_PER_BLOCK;   // 1024

    yolo_loss_kernel<<<blocks, 256, 0, stream>>>(outp, tgtp, ws, nchunks, nwaves);
    yolo_reduce_kernel<<<1, 256, 0, stream>>>(ws, o, nwaves);
}